// Round 3
// baseline (700.692 us; speedup 1.0000x reference)
//
#include <hip/hip_runtime.h>
#include <hip/hip_bf16.h>
#include <cstdint>
#include <cstddef>

// ---------------- model constants ----------------
#define TH 0.007f

// ---------------- workspace layout (float offsets) ----------------
#define OFF_S1RAW   0u          // 128*100*64
#define OFF_S2RAW   819200u
#define OFF_GRU1O   2457600u    // 128*200*64
#define OFF_GRU2O   4096000u
#define OFF_XP1     5734400u    // 128*100*192
#define OFF_XP2     8192000u
#define OFF_ZP1     10649600u   // 100*192
#define OFF_ZP2     10668800u
#define OFF_ZINC1   10688000u   // 100*64
#define OFF_ZINC2   10694400u
#define OFF_ZITC1   10700800u   // 200*64
#define OFF_ZITC2   10713600u
#define OFF_G3      10726400u   // 3*128

__device__ __forceinline__ float sigf(float x) { return 1.0f / (1.0f + __expf(-x)); }
__device__ __forceinline__ float tanhf_(float x) { return 1.0f - 2.0f / (__expf(2.0f * x) + 1.0f); }

// ---------------- 1) gathers: s1raw, s2raw ----------------
__global__ void k_gather(const int* __restrict__ seq1, const int* __restrict__ seq2,
                         const float* __restrict__ emb, float* __restrict__ ws) {
  int tid = threadIdx.x;
  int r = blockIdx.x * 4 + (tid >> 6);
  int d = tid & 63;
  long idx;
  float* dst;
  if (r < 12800) {
    idx = seq1[r];
    dst = ws + OFF_S1RAW + (size_t)r * 64;
  } else {
    int rr = r - 12800;
    idx = seq2[rr];
    dst = ws + OFF_S2RAW + (size_t)rr * 64;
  }
  dst[d] = emb[idx * 64 + d];
}

// ---------------- 2) per-batch max pairwise dot ----------------
__global__ __launch_bounds__(256) void k_gmax(const float* __restrict__ A0, const float* __restrict__ B0, float* g0,
                                              const float* __restrict__ A1, const float* __restrict__ B1, float* g1,
                                              int L, int nbhalf) {
  int half = blockIdx.x / nbhalf;
  int b = blockIdx.x % nbhalf;
  const float* A = half ? A1 : A0;
  const float* B = half ? B1 : B0;
  float* gout = half ? g1 : g0;
  __shared__ __align__(16) float SA[64 * 104];
  __shared__ __align__(16) float SB[64 * 104];
  __shared__ float red[4];
  int tid = threadIdx.x;
  int nch = L / 100;
  float gm = -1e30f;
  for (int ai = 0; ai < nch; ++ai) {
    for (int bi = 0; bi < nch; ++bi) {
      __syncthreads();
      for (int e = tid; e < 6400; e += 256) {
        int l = e >> 6, k = e & 63;
        SA[k * 104 + l] = A[((size_t)b * L + ai * 100 + l) * 64 + k];
        SB[k * 104 + l] = B[((size_t)b * L + bi * 100 + l) * 64 + k];
      }
      __syncthreads();
      for (int id = tid; id < 625; id += 256) {
        int ti = id / 25, tj = id % 25;
        int l0 = ti * 4, m0 = tj * 4;
        float acc[4][4];
#pragma unroll
        for (int x = 0; x < 4; ++x)
#pragma unroll
          for (int y = 0; y < 4; ++y) acc[x][y] = 0.0f;
#pragma unroll 16
        for (int k = 0; k < 64; ++k) {
          const float4 av = *reinterpret_cast<const float4*>(&SA[k * 104 + l0]);
          const float4 bv = *reinterpret_cast<const float4*>(&SB[k * 104 + m0]);
          float aa[4] = {av.x, av.y, av.z, av.w};
          float bb[4] = {bv.x, bv.y, bv.z, bv.w};
#pragma unroll
          for (int x = 0; x < 4; ++x)
#pragma unroll
            for (int y = 0; y < 4; ++y) acc[x][y] = fmaf(aa[x], bb[y], acc[x][y]);
        }
        float tm = acc[0][0];
#pragma unroll
        for (int x = 0; x < 4; ++x)
#pragma unroll
          for (int y = 0; y < 4; ++y) tm = fmaxf(tm, acc[x][y]);
        gm = fmaxf(gm, tm);
      }
    }
  }
  for (int off = 32; off; off >>= 1) gm = fmaxf(gm, __shfl_xor(gm, off, 64));
  if ((tid & 63) == 0) red[tid >> 6] = gm;
  __syncthreads();
  if (tid == 0) gout[b] = fmaxf(fmaxf(red[0], red[1]), fmaxf(red[2], red[3]));
}

// ---------------- 3) z (with fused softmax mask): one wave per (comp,l) ----------------
__global__ void k_z(const float* o0, const float* g0, const float* Wbs0, const float* Wnn0, const float* bnn0, const float* bbs0, float* z0,
                    const float* o1, const float* g1, const float* Wbs1, const float* Wnn1, const float* bnn1, const float* bbs1, float* z1,
                    int L) {
  int comp = blockIdx.x / L;
  int l = blockIdx.x % L;
  const float* other = comp ? o1 : o0;
  const float* g = comp ? g1 : g0;
  const float* Wbs = comp ? Wbs1 : Wbs0;
  const float* Wnn = comp ? Wnn1 : Wnn0;
  const float* bnn = comp ? bnn1 : bnn0;
  const float* bbs = comp ? bbs1 : bbs0;
  float* zout = comp ? z1 : z0;
  int d = threadIdx.x;  // one wave
  __shared__ float w_s[128];
  __shared__ float tl[64];
  float ga = g[d], gb = g[d + 64];
  float mx = fmaxf(ga, gb);
  for (int off = 32; off; off >>= 1) mx = fmaxf(mx, __shfl_xor(mx, off, 64));
  float ea = __expf(ga - mx), eb = __expf(gb - mx);
  float sm = ea + eb;
  for (int off = 32; off; off >>= 1) sm += __shfl_xor(sm, off, 64);
  float wa = Wbs[d], wb = Wbs[d + 64];
  w_s[d] = (ea / sm > TH) ? wa : 0.0f;
  w_s[d + 64] = (eb / sm > TH) ? wb : 0.0f;
  float cs = wa + wb;
  for (int off = 32; off; off >>= 1) cs += __shfl_xor(cs, off, 64);
  __syncthreads();
  float td = 0.0f;
#pragma unroll 4
  for (int j = 0; j < 128; ++j) td = fmaf(w_s[j], other[((size_t)j * L + l) * 64 + d], td);
  tl[d] = td;
  __syncthreads();
  float acc = fmaf(cs, bnn[d], bbs[0]);
#pragma unroll 8
  for (int k = 0; k < 64; ++k) acc = fmaf(tl[k], Wnn[d * 64 + k], acc);
  zout[l * 64 + d] = acc;
}

// ---------------- 4) input projections: out = X @ Wih^T + bih ----------------
__global__ __launch_bounds__(192) void k_xproj(const float* __restrict__ s1raw, const float* __restrict__ s2raw,
                                               const float* __restrict__ zi1, const float* __restrict__ zi2,
                                               const float* __restrict__ W1, const float* __restrict__ b1,
                                               const float* __restrict__ W2, const float* __restrict__ b2,
                                               float* xp1, float* xp2, float* zp1, float* zp2) {
  int blk = blockIdx.x;
  const float* X;
  const float* W;
  const float* bi;
  float* out;
  int nrows, lb;
  if (blk < 800)        { X = s1raw; W = W1; bi = b1; out = xp1; nrows = 12800; lb = blk; }
  else if (blk < 1600)  { X = s2raw; W = W2; bi = b2; out = xp2; nrows = 12800; lb = blk - 800; }
  else if (blk < 1607)  { X = zi1;   W = W1; bi = b1; out = zp1; nrows = 100;   lb = blk - 1600; }
  else                  { X = zi2;   W = W2; bi = b2; out = zp2; nrows = 100;   lb = blk - 1607; }
  int row0 = lb * 16;
  int j = threadIdx.x;  // 0..191
  __shared__ float xt[16 * 64];
  int rmax = nrows - row0;
  if (rmax > 16) rmax = 16;
  int lim = rmax * 64;
  for (int e = j; e < lim; e += 192) xt[e] = X[(size_t)row0 * 64 + e];
  __syncthreads();
  float wreg[64];
#pragma unroll
  for (int k = 0; k < 64; ++k) wreg[k] = W[j * 64 + k];
  float bj = bi[j];
  for (int r = 0; r < rmax; ++r) {
    float acc = bj;
#pragma unroll
    for (int k = 0; k < 64; ++k) acc = fmaf(xt[r * 64 + k], wreg[k], acc);
    out[(size_t)(row0 + r) * 192 + j] = acc;
  }
}

// ---------------- 5) GRU scan: single wave, barrier-free ----------------
// lane i: r-row in VGPR; z-row, n-row in XOR-swizzled LDS; h broadcast via
// same-address LDS float4 reads. No __syncthreads -> no vmcnt drain per step.
__device__ __forceinline__ int swz(int row, int k4) {
  return row * 64 + ((k4 * 4) ^ ((row & 7) * 4));
}
__global__ __launch_bounds__(64, 1) void k_scan(const float* __restrict__ xp1, const float* __restrict__ xp2,
                                                const float* __restrict__ zp1, const float* __restrict__ zp2,
                                                const float* __restrict__ Whh1, const float* __restrict__ bhh1,
                                                const float* __restrict__ Whh2, const float* __restrict__ bhh2,
                                                float* o1, float* o2) {
  int dom = blockIdx.x >> 7;
  int bb = blockIdx.x & 127;
  const float* xp = dom ? xp2 : xp1;
  const float* zp = dom ? zp2 : zp1;
  const float* Whh = dom ? Whh2 : Whh1;
  const float* bhh = dom ? bhh2 : bhh1;
  float* out = (dom ? o2 : o1) + (size_t)bb * 200 * 64;
  int i = threadIdx.x;
  __shared__ __align__(16) float wz_s[64 * 64];
  __shared__ __align__(16) float wn_s[64 * 64];
  __shared__ __align__(16) float h_s[64];
  // stage: r-row -> regs; z-row, n-row -> swizzled LDS
  float4 wr4[16];
#pragma unroll
  for (int k4 = 0; k4 < 16; ++k4) {
    wr4[k4] = *reinterpret_cast<const float4*>(Whh + (size_t)i * 64 + k4 * 4);
    *reinterpret_cast<float4*>(&wz_s[swz(i, k4)]) =
        *reinterpret_cast<const float4*>(Whh + (size_t)(64 + i) * 64 + k4 * 4);
    *reinterpret_cast<float4*>(&wn_s[swz(i, k4)]) =
        *reinterpret_cast<const float4*>(Whh + (size_t)(128 + i) * 64 + k4 * 4);
  }
  float br = bhh[i], bz = bhh[64 + i], bn = bhh[128 + i];
  float h = 0.0f;
  h_s[i] = 0.0f;
  const float* p0 = xp + (size_t)bb * 100 * 192;
  float xr = p0[i], xz = p0[64 + i], xn = p0[128 + i];
  for (int t = 0; t < 200; ++t) {
    float nxr = 0.f, nxz = 0.f, nxn = 0.f;
    if (t < 199) {
      const float* pn = (t < 99) ? xp + ((size_t)bb * 100 + t + 1) * 192
                                 : zp + (size_t)(t + 1 - 100) * 192;
      nxr = pn[i]; nxz = pn[64 + i]; nxn = pn[128 + i];
    }
    float ar0 = br, ar1 = 0.f, az0 = bz, az1 = 0.f, an0 = bn, an1 = 0.f;
#pragma unroll
    for (int k4 = 0; k4 < 16; ++k4) {
      const float4 hv = *reinterpret_cast<const float4*>(&h_s[k4 * 4]);  // broadcast
      const float4 zv = *reinterpret_cast<const float4*>(&wz_s[swz(i, k4)]);
      const float4 nv = *reinterpret_cast<const float4*>(&wn_s[swz(i, k4)]);
      ar0 = fmaf(hv.x, wr4[k4].x, ar0); ar1 = fmaf(hv.y, wr4[k4].y, ar1);
      ar0 = fmaf(hv.z, wr4[k4].z, ar0); ar1 = fmaf(hv.w, wr4[k4].w, ar1);
      az0 = fmaf(hv.x, zv.x, az0);      az1 = fmaf(hv.y, zv.y, az1);
      az0 = fmaf(hv.z, zv.z, az0);      az1 = fmaf(hv.w, zv.w, az1);
      an0 = fmaf(hv.x, nv.x, an0);      an1 = fmaf(hv.y, nv.y, an1);
      an0 = fmaf(hv.z, nv.z, an0);      an1 = fmaf(hv.w, nv.w, an1);
    }
    float r = sigf(xr + ar0 + ar1);
    float z = sigf(xz + az0 + az1);
    float n = tanhf_(xn + r * (an0 + an1));
    h = n + z * (h - n);
    out[t * 64 + i] = h;
    h_s[i] = h;   // next iter's broadcast reads depend on this (in-wave lgkm dep)
    xr = nxr; xz = nxz; xn = nxn;
  }
}

// ---------------- 6) predictor MLP (u-mean fused; V direct from emb) ----------------
__global__ __launch_bounds__(256) void k_pred(const float* __restrict__ g1o, const float* __restrict__ g2o,
                                              const float* __restrict__ zi1, const float* __restrict__ zi2,
                                              const int* __restrict__ i_node, const int* __restrict__ neg,
                                              const float* __restrict__ emb,
                                              const float* __restrict__ W1, const float* __restrict__ b1v,
                                              const float* __restrict__ w2v, const float* __restrict__ b2v,
                                              float* __restrict__ outp) {
  int p = blockIdx.x >> 7, bb = blockIdx.x & 127;
  const float* s = p ? g2o : g1o;
  const float* zz = p ? zi2 : zi1;
  int tid = threadIdx.x;
  __shared__ float up[4][64];
  __shared__ float u_s[64];
  __shared__ float aU[128];
  __shared__ float part[2][100];
  // u = (sum_t gru[bb] + sum_l z)/400, split over 4 chunks of 50
  {
    int d = tid & 63, c = tid >> 6;
    float acc = 0.0f;
    const float* sp = s + (size_t)bb * 12800 + c * 50 * 64 + d;
#pragma unroll 2
    for (int t = 0; t < 50; ++t) acc += sp[t * 64];
    const float* zp = zz + c * 50 * 64 + d;
#pragma unroll 2
    for (int t = 0; t < 50; ++t) acc += zp[t * 64];
    up[c][d] = acc;
  }
  __syncthreads();
  if (tid < 64) u_s[tid] = (up[0][tid] + up[1][tid] + up[2][tid] + up[3][tid]) * 0.0025f;
  __syncthreads();
  // aU[j] = b1[j] + u . W1[j,:64]
  if (tid < 128) {
    float acc = b1v[tid];
#pragma unroll 8
    for (int k = 0; k < 64; ++k) acc = fmaf(u_s[k], W1[tid * 128 + k], acc);
    aU[tid] = acc;
  }
  int lane = tid & 63;
  int jh = (tid >> 6) & 1;
  int ih = tid >> 7;
  int i = ih * 64 + lane;
  bool act = i < 100;
  long idx = act ? (long)((i == 0) ? i_node[bb] : neg[bb * 99 + i - 1]) : 0;
  float V[64];
  const float* vp = emb + (size_t)idx * 64;
#pragma unroll
  for (int k4 = 0; k4 < 16; ++k4) {
    float4 vv = *reinterpret_cast<const float4*>(vp + 4 * k4);
    V[4 * k4 + 0] = vv.x; V[4 * k4 + 1] = vv.y; V[4 * k4 + 2] = vv.z; V[4 * k4 + 3] = vv.w;
  }
  __syncthreads();
  float acc_o = 0.0f;
  for (int j = jh * 64; j < jh * 64 + 64; ++j) {
    const float* wrow = W1 + j * 128 + 64;  // wave-uniform -> s_load
    float d0 = aU[j], d1 = 0.0f, d2 = 0.0f, d3 = 0.0f;
#pragma unroll
    for (int k = 0; k < 16; ++k) {
      d0 = fmaf(V[4 * k + 0], wrow[4 * k + 0], d0);
      d1 = fmaf(V[4 * k + 1], wrow[4 * k + 1], d1);
      d2 = fmaf(V[4 * k + 2], wrow[4 * k + 2], d2);
      d3 = fmaf(V[4 * k + 3], wrow[4 * k + 3], d3);
    }
    float hrelu = fmaxf((d0 + d1) + (d2 + d3), 0.0f);
    acc_o = fmaf(w2v[j], hrelu, acc_o);
  }
  if (act) part[jh][i] = acc_o;
  __syncthreads();
  if (act && jh == 0) {
    float sres = part[0][i] + part[1][i] + b2v[0];
    outp[(size_t)p * 12800 + bb * 100 + i] = 1.0f / (1.0f + __expf(-sres));
  }
}

// ---------------- launcher ----------------
extern "C" void kernel_launch(void* const* d_in, const int* in_sizes, int n_in,
                              void* d_out, int out_size, void* d_ws, size_t ws_size,
                              hipStream_t stream) {
  const int* i_node = (const int*)d_in[1];
  const int* neg = (const int*)d_in[2];
  const int* seq1 = (const int*)d_in[3];
  const int* seq2 = (const int*)d_in[4];
  const float* emb = (const float*)d_in[7];
  const float* inc1_Wnn = (const float*)d_in[8];
  const float* inc1_bnn = (const float*)d_in[9];
  const float* inc1_Wbs = (const float*)d_in[10];
  const float* inc1_bbs = (const float*)d_in[11];
  const float* inc2_Wnn = (const float*)d_in[12];
  const float* inc2_bnn = (const float*)d_in[13];
  const float* inc2_Wbs = (const float*)d_in[14];
  const float* inc2_bbs = (const float*)d_in[15];
  const float* itc1_Wnn = (const float*)d_in[16];
  const float* itc1_bnn = (const float*)d_in[17];
  const float* itc1_Wbs = (const float*)d_in[18];
  const float* itc1_bbs = (const float*)d_in[19];
  const float* itc2_Wnn = (const float*)d_in[20];
  const float* itc2_bnn = (const float*)d_in[21];
  const float* itc2_Wbs = (const float*)d_in[22];
  const float* itc2_bbs = (const float*)d_in[23];
  const float* gru1_Wih = (const float*)d_in[24];
  const float* gru1_Whh = (const float*)d_in[25];
  const float* gru1_bih = (const float*)d_in[26];
  const float* gru1_bhh = (const float*)d_in[27];
  const float* gru2_Wih = (const float*)d_in[28];
  const float* gru2_Whh = (const float*)d_in[29];
  const float* gru2_bih = (const float*)d_in[30];
  const float* gru2_bhh = (const float*)d_in[31];
  const float* fc1_W = (const float*)d_in[32];
  const float* fc1_b = (const float*)d_in[33];
  const float* fc2_W = (const float*)d_in[34];
  const float* fc2_b = (const float*)d_in[35];

  float* ws = (float*)d_ws;
  float* out = (float*)d_out;
  float* s1raw = ws + OFF_S1RAW;
  float* s2raw = ws + OFF_S2RAW;
  float* gru1o = ws + OFF_GRU1O;
  float* gru2o = ws + OFF_GRU2O;
  float* xp1 = ws + OFF_XP1;
  float* xp2 = ws + OFF_XP2;
  float* zp1 = ws + OFF_ZP1;
  float* zp2 = ws + OFF_ZP2;
  float* zinc1 = ws + OFF_ZINC1;
  float* zinc2 = ws + OFF_ZINC2;
  float* zitc1 = ws + OFF_ZITC1;
  float* zitc2 = ws + OFF_ZITC2;
  float* g3 = ws + OFF_G3;

  // 1) seq gathers
  k_gather<<<6400, 256, 0, stream>>>(seq1, seq2, emb, ws);
  // 2) inner-comp g (self-Gram max) for both domains
  k_gmax<<<256, 256, 0, stream>>>(s1raw, s1raw, g3, s2raw, s2raw, g3 + 128, 100, 128);
  // 3) z for inner comps (mask fused)
  k_z<<<200, 64, 0, stream>>>(s1raw, g3, inc1_Wbs, inc1_Wnn, inc1_bnn, inc1_bbs, zinc1,
                              s2raw, g3 + 128, inc2_Wbs, inc2_Wnn, inc2_bnn, inc2_bbs, zinc2, 100);
  // 4) GRU input projections
  k_xproj<<<1614, 192, 0, stream>>>(s1raw, s2raw, zinc1, zinc2,
                                    gru1_Wih, gru1_bih, gru2_Wih, gru2_bih,
                                    xp1, xp2, zp1, zp2);
  // 5) GRU scans (single wave per chain, barrier-free)
  k_scan<<<256, 64, 0, stream>>>(xp1, xp2, zp1, zp2, gru1_Whh, gru1_bhh, gru2_Whh, gru2_bhh,
                                 gru1o, gru2o);
  // 6) inter-comp g (shared by itc1/itc2)
  k_gmax<<<128, 256, 0, stream>>>(gru1o, gru2o, g3 + 256, gru1o, gru2o, g3 + 256, 200, 128);
  // 7) z for inter comps (mask fused; itc1 uses gru2 output, itc2 uses gru1 output)
  k_z<<<400, 64, 0, stream>>>(gru2o, g3 + 256, itc1_Wbs, itc1_Wnn, itc1_bnn, itc1_bbs, zitc1,
                              gru1o, g3 + 256, itc2_Wbs, itc2_Wnn, itc2_bnn, itc2_bbs, zitc2, 200);
  // 8) predictor (u-mean fused; item embeddings read directly)
  k_pred<<<256, 256, 0, stream>>>(gru1o, gru2o, zitc1, zitc2, i_node, neg, emb,
                                  fc1_W, fc1_b, fc2_W, fc2_b, out);
}